// Round 2
// baseline (690.374 us; speedup 1.0000x reference)
//
#include <hip/hip_runtime.h>

// voltageNN: 5-layer projected LSTM (H=256, P=1) over T=1000, B=128 + MLP head.
// All I/O is f32 (per reference dtypes; R1 confirmed bf16 reading produces 1e8 garbage).
// Design: 1 block per batch element; systolic layer pipeline inside the block.
//   waves 0-3 : layers 0-3, 4 hidden units per thread (j = k*64 + lane)
//   waves 4-7 : layer 4 split into 4 quarters, 1 hidden unit per thread
// One __syncthreads per pipeline iteration (T+L total), double-buffered LDS h slots.

#define HSZ 256
#define LAYERS 5
#define TT 1000
#define BATCH 128

__device__ __forceinline__ float fast_exp2(float x) {
#if __has_builtin(__builtin_amdgcn_exp2f)
  return __builtin_amdgcn_exp2f(x);
#else
  return __exp2f(x);
#endif
}
__device__ __forceinline__ float fast_rcp(float x) {
#if __has_builtin(__builtin_amdgcn_rcpf)
  return __builtin_amdgcn_rcpf(x);
#else
  return 1.0f / x;
#endif
}
// sigmoid(z) = 1/(1+exp2(-z*log2e)); graceful at +-inf (exp2->inf -> rcp->0)
__device__ __forceinline__ float fast_sigmoid(float z) {
  float e = fast_exp2(-1.4426950408889634f * z);
  return fast_rcp(1.0f + e);
}
// tanh(z) = 2*sigmoid(2z)-1 ; safe for large |z|
__device__ __forceinline__ float fast_tanh(float z) {
  float e = fast_exp2(-2.8853900817779268f * z);
  return fmaf(2.0f, fast_rcp(1.0f + e), -1.0f);
}

template <int CTRL>
__device__ __forceinline__ float dpp_add(float v) {
  int moved = __builtin_amdgcn_update_dpp(0, __builtin_bit_cast(int, v),
                                          CTRL, 0xF, 0xF, false);
  return v + __builtin_bit_cast(float, moved);
}

// Full wave64 sum, broadcast to all lanes.
// 4x DPP row-rotate adds (row-of-16 sums) + ds_swizzle xor16 + 2x readlane.
__device__ __forceinline__ float wave_sum(float v) {
  v = dpp_add<0x128>(v);  // row_ror:8
  v = dpp_add<0x124>(v);  // row_ror:4
  v = dpp_add<0x122>(v);  // row_ror:2
  v = dpp_add<0x121>(v);  // row_ror:1  -> each lane = its row-of-16 sum
  int sw = __builtin_amdgcn_ds_swizzle(__builtin_bit_cast(int, v), 0x401F);  // lane^16
  v = v + __builtin_bit_cast(float, sw);  // each lane = its 32-half sum
  float lo = __builtin_bit_cast(float, __builtin_amdgcn_readlane(__builtin_bit_cast(int, v), 0));
  float hi = __builtin_bit_cast(float, __builtin_amdgcn_readlane(__builtin_bit_cast(int, v), 32));
  return lo + hi;
}

__global__ __launch_bounds__(512) void lstm_pipeline_kernel(
    const float* __restrict__ x,     // [B, T]
    const float* __restrict__ Wih,   // [L, 1024]
    const float* __restrict__ Whh,   // [L, 1024]
    const float* __restrict__ bih,   // [L, 1024]
    const float* __restrict__ bhh,   // [L, 1024]
    const float* __restrict__ Whr,   // [L, 256]
    float* __restrict__ seq_out)     // [B, T] f32 (workspace)
{
  __shared__ float xs[TT];
  __shared__ float part[2][4];                       // h of layers 0..3, double-buffered
  __shared__ __align__(16) float part4[2][4];        // layer-4 quarter partials

  const int b    = blockIdx.x;
  const int tid  = threadIdx.x;
  const int wave = tid >> 6;
  const int lane = tid & 63;
  const bool big = (wave < 4);
  const int layer = big ? wave : 4;
  const int nq    = wave - 4;  // quarter index for layer-4 waves

  // stage x row into LDS
  for (int i = tid; i < TT; i += 512) xs[i] = x[b * TT + i];
  if (tid < 8) { ((float*)part)[tid] = 0.0f; ((float*)part4)[tid] = 0.0f; }

  // per-thread weight registers
  float wi[4][4], wh[4][4], bs[4][4], whr[4], c[4];
  const int base = layer * 1024;
  if (big) {
#pragma unroll
    for (int g = 0; g < 4; ++g)
#pragma unroll
      for (int k = 0; k < 4; ++k) {
        int j = base + g * 256 + k * 64 + lane;
        wi[g][k] = Wih[j];
        wh[g][k] = Whh[j];
        bs[g][k] = bih[j] + bhh[j];
      }
#pragma unroll
    for (int k = 0; k < 4; ++k) {
      whr[k] = Whr[layer * 256 + k * 64 + lane];
      c[k] = 0.0f;
    }
  } else {
#pragma unroll
    for (int g = 0; g < 4; ++g) {
      int j = base + g * 256 + nq * 64 + lane;
      wi[g][0] = Wih[j];
      wh[g][0] = Whh[j];
      bs[g][0] = bih[j] + bhh[j];
#pragma unroll
      for (int k = 1; k < 4; ++k) { wi[g][k] = 0.f; wh[g][k] = 0.f; bs[g][k] = 0.f; }
    }
    whr[0] = Whr[4 * 256 + nq * 64 + lane];
#pragma unroll
    for (int k = 0; k < 4; ++k) c[k] = 0.0f;
#pragma unroll
    for (int k = 1; k < 4; ++k) whr[k] = 0.0f;
  }
  float h_own = 0.0f;
  __syncthreads();

  auto cell = [&](int k, float x_in) -> float {
    float pi = fmaf(x_in, wi[0][k], fmaf(h_own, wh[0][k], bs[0][k]));
    float pf = fmaf(x_in, wi[1][k], fmaf(h_own, wh[1][k], bs[1][k]));
    float pg = fmaf(x_in, wi[2][k], fmaf(h_own, wh[2][k], bs[2][k]));
    float po = fmaf(x_in, wi[3][k], fmaf(h_own, wh[3][k], bs[3][k]));
    float ig = fast_sigmoid(pi);
    float fg = fast_sigmoid(pf);
    float gg = fast_tanh(pg);
    float og = fast_sigmoid(po);
    c[k] = fmaf(fg, c[k], ig * gg);
    return og * fast_tanh(c[k]) * whr[k];
  };

  // pipeline: at iteration it, layer l processes t = it - l
  for (int it = 0; it < TT + LAYERS; ++it) {
    const int p  = it & 1;
    const int p1 = (it - 1) & 1;
    const int t  = it - layer;

    if (!big) {
      // combine last iteration's 4 quarter partials -> h4(t-1)
      float4 q = *(const float4*)&part4[p1][0];
      h_own = (q.x + q.y) + (q.z + q.w);
      if (nq == 0 && lane == 0) {
        int tp = it - 1 - 4;  // time index h_own corresponds to
        if (tp >= 0 && tp < TT) seq_out[b * TT + tp] = h_own;
      }
    }

    const bool active = (t >= 0) && (t < TT);
    if (active) {
      float x_in = (layer == 0) ? xs[t]
                 : (big ? part[p1][layer - 1] : part[p1][3]);
      float r;
      if (big) {
        r = 0.0f;
#pragma unroll
        for (int k = 0; k < 4; ++k) r += cell(k, x_in);
      } else {
        r = cell(0, x_in);
      }
      r = wave_sum(r);
      if (big) {
        h_own = r;  // full 256-sum: this layer's h(t)
        if (lane == 0) part[p][layer] = r;
      } else {
        if (lane == 0) part4[p][nq] = r;  // 64-sum quarter partial
      }
    }
    __syncthreads();
  }
}

__global__ __launch_bounds__(128) void mlp_head_kernel(
    const float* __restrict__ seq,   // [B, T] f32 (workspace)
    const float* __restrict__ W1, const float* __restrict__ b1,
    const float* __restrict__ W2, const float* __restrict__ b2,
    const float* __restrict__ W3, const float* __restrict__ b3,
    const float* __restrict__ W4, const float* __restrict__ b4,
    float* __restrict__ out)         // [B]
{
  __shared__ float sx[TT];
  __shared__ float sh[100];
  __shared__ float sh2[100];
  __shared__ float red[2];

  const int b = blockIdx.x, tid = threadIdx.x;
  for (int i = tid; i < TT; i += 128) sx[i] = seq[b * TT + i];
  __syncthreads();

  // h1 = sigmoid(seq @ W1.T + b1), 100 outputs; float4 loads of W1 rows
  if (tid < 100) {
    float acc = b1[tid];
    const float* w = W1 + tid * TT;  // byte offset 4000*tid, 16B aligned
    for (int t0 = 0; t0 < TT; t0 += 4) {
      float4 v = *(const float4*)(w + t0);
      acc += v.x * sx[t0 + 0];
      acc += v.y * sx[t0 + 1];
      acc += v.z * sx[t0 + 2];
      acc += v.w * sx[t0 + 3];
    }
    sh[tid] = fast_sigmoid(acc);
  }
  __syncthreads();

  if (tid < 100) {
    float acc = b2[tid];
    const float* w = W2 + tid * 100;
    for (int k = 0; k < 100; ++k) acc += w[k] * sh[k];
    sh2[tid] = fast_sigmoid(acc);
  }
  __syncthreads();

  if (tid < 100) {
    float acc = b3[tid];
    const float* w = W3 + tid * 100;
    for (int k = 0; k < 100; ++k) acc += w[k] * sh2[k];
    sh[tid] = fmaxf(acc, 0.0f);  // reuse sh as h3
  }
  __syncthreads();

  float r = (tid < 100) ? sh[tid] * W4[tid] : 0.0f;
  r = wave_sum(r);
  if ((tid & 63) == 0) red[tid >> 6] = r;
  __syncthreads();
  if (tid == 0) out[b] = red[0] + red[1] + b4[0];
}

extern "C" void kernel_launch(void* const* d_in, const int* in_sizes, int n_in,
                              void* d_out, int out_size, void* d_ws, size_t ws_size,
                              hipStream_t stream) {
  const float* x   = (const float*)d_in[0];
  const float* Wih = (const float*)d_in[1];
  const float* Whh = (const float*)d_in[2];
  const float* bih = (const float*)d_in[3];
  const float* bhh = (const float*)d_in[4];
  const float* Whr = (const float*)d_in[5];
  const float* W1  = (const float*)d_in[6];
  const float* b1  = (const float*)d_in[7];
  const float* W2  = (const float*)d_in[8];
  const float* b2  = (const float*)d_in[9];
  const float* W3  = (const float*)d_in[10];
  const float* b3  = (const float*)d_in[11];
  const float* W4  = (const float*)d_in[12];
  const float* b4  = (const float*)d_in[13];

  float* seq = (float*)d_ws;  // [128][1000] f32 = 512 KB

  lstm_pipeline_kernel<<<BATCH, 512, 0, stream>>>(x, Wih, Whh, bih, bhh, Whr, seq);
  mlp_head_kernel<<<BATCH, 128, 0, stream>>>(seq, W1, b1, W2, b2, W3, b3, W4, b4,
                                             (float*)d_out);
}

// Round 3
// 625.638 us; speedup vs baseline: 1.1035x; 1.1035x over previous
//
#include <hip/hip_runtime.h>

// voltageNN: 5-layer projected LSTM (H=256, P=1) over T=1000, B=128 + MLP head.
// R3 design: decoupled software pipeline. 640 blocks of 1 wave, one per
// (layer, batch). Each wave owns a full layer (4 hidden units/lane), runs the
// recurrence in-register over chunks of CH timesteps (no intra-chunk sync),
// and hands chunks to the next layer through global memory with agent-scope
// release/acquire flags. No __syncthreads anywhere in the LSTM.
// Mapping bid = b + 128*l co-locates a batch's pipeline on one XCD (128%8==0)
// -- locality heuristic only; correctness relies solely on agent-scope atomics.

#define LAYERS 5
#define TT 1000
#define BATCH 128
#define CH 40            // chunk length (divides TT)
#define NCH (TT / CH)    // 25 chunks

__device__ __forceinline__ float fast_exp2(float x) {
#if __has_builtin(__builtin_amdgcn_exp2f)
  return __builtin_amdgcn_exp2f(x);
#else
  return __exp2f(x);
#endif
}
__device__ __forceinline__ float fast_rcp(float x) {
#if __has_builtin(__builtin_amdgcn_rcpf)
  return __builtin_amdgcn_rcpf(x);
#else
  return 1.0f / x;
#endif
}
// sigmoid(z) = 1/(1+exp2(-z*log2e)); graceful at +-inf
__device__ __forceinline__ float fast_sigmoid(float z) {
  float e = fast_exp2(-1.4426950408889634f * z);
  return fast_rcp(1.0f + e);
}
// tanh(z) = 2*sigmoid(2z)-1 ; safe for large |z|
__device__ __forceinline__ float fast_tanh(float z) {
  float e = fast_exp2(-2.8853900817779268f * z);
  return fmaf(2.0f, fast_rcp(1.0f + e), -1.0f);
}

template <int CTRL>
__device__ __forceinline__ float dpp_add(float v) {
  int moved = __builtin_amdgcn_update_dpp(0, __builtin_bit_cast(int, v),
                                          CTRL, 0xF, 0xF, false);
  return v + __builtin_bit_cast(float, moved);
}

// Full wave64 sum, broadcast to all lanes (proven in R2: absmax == 0).
__device__ __forceinline__ float wave_sum(float v) {
  v = dpp_add<0x128>(v);  // row_ror:8
  v = dpp_add<0x124>(v);  // row_ror:4
  v = dpp_add<0x122>(v);  // row_ror:2
  v = dpp_add<0x121>(v);  // row_ror:1  -> each lane = its row-of-16 sum
  int sw = __builtin_amdgcn_ds_swizzle(__builtin_bit_cast(int, v), 0x401F);  // lane^16
  v = v + __builtin_bit_cast(float, sw);  // each lane = its 32-half sum
  float lo = __builtin_bit_cast(float, __builtin_amdgcn_readlane(__builtin_bit_cast(int, v), 0));
  float hi = __builtin_bit_cast(float, __builtin_amdgcn_readlane(__builtin_bit_cast(int, v), 32));
  return lo + hi;
}

__device__ __forceinline__ float lane_bcast(float v, int s) {
  return __builtin_bit_cast(float, __builtin_amdgcn_readlane(__builtin_bit_cast(int, v), s));
}

__global__ __launch_bounds__(64) void lstm_wave_kernel(
    const float* __restrict__ x,     // [B, T]
    const float* __restrict__ Wih,   // [L, 1024]
    const float* __restrict__ Whh,   // [L, 1024]
    const float* __restrict__ bih,   // [L, 1024]
    const float* __restrict__ bhh,   // [L, 1024]
    const float* __restrict__ Whr,   // [L, 256]
    float* __restrict__ seq,         // [L, B, T] layer outputs (workspace)
    int* __restrict__ flags)         // [L, B] chunk progress counters
{
  const int bid  = blockIdx.x;
  const int l    = bid >> 7;   // bid / 128
  const int b    = bid & 127;  // bid % 128
  const int lane = threadIdx.x;

  // per-lane weights: hidden unit j = k*64 + lane, gate g
  float wi[4][4], wh[4][4], bs[4][4], whr[4], cc[4];
  const int base = l * 1024;
#pragma unroll
  for (int g = 0; g < 4; ++g)
#pragma unroll
    for (int k = 0; k < 4; ++k) {
      int j = base + g * 256 + k * 64 + lane;
      wi[g][k] = Wih[j];
      wh[g][k] = Whh[j];
      bs[g][k] = bih[j] + bhh[j];
    }
#pragma unroll
  for (int k = 0; k < 4; ++k) {
    whr[k] = Whr[l * 256 + k * 64 + lane];
    cc[k] = 0.0f;
  }

  const float* in  = (l == 0) ? (x + b * TT) : (seq + ((l - 1) * BATCH + b) * TT);
  float*       out = seq + (l * BATCH + b) * TT;
  int*       my_flag = flags + l * BATCH + b;
  const int* in_flag = (l > 0) ? (flags + (l - 1) * BATCH + b) : (const int*)flags;

  float h = 0.0f;
  for (int c = 0; c < NCH; ++c) {
    // wait for producer's chunk c (wave-uniform spin; layer 0 reads x directly)
    if (l > 0) {
      while (__hip_atomic_load(in_flag, __ATOMIC_ACQUIRE,
                               __HIP_MEMORY_SCOPE_AGENT) <= c)
        __builtin_amdgcn_s_sleep(2);
    }
    // fetch CH inputs, one per lane
    float xv = 0.0f;
    if (lane < CH) {
      if (l == 0)
        xv = in[c * CH + lane];
      else
        xv = __hip_atomic_load(in + c * CH + lane, __ATOMIC_RELAXED,
                               __HIP_MEMORY_SCOPE_AGENT);
    }

    float outv = 0.0f;
    for (int s = 0; s < CH; ++s) {
      const float xs = lane_bcast(xv, s);  // uniform broadcast of input t
      float r = 0.0f;
#pragma unroll
      for (int k = 0; k < 4; ++k) {
        float pi = fmaf(xs, wi[0][k], fmaf(h, wh[0][k], bs[0][k]));
        float pf = fmaf(xs, wi[1][k], fmaf(h, wh[1][k], bs[1][k]));
        float pg = fmaf(xs, wi[2][k], fmaf(h, wh[2][k], bs[2][k]));
        float po = fmaf(xs, wi[3][k], fmaf(h, wh[3][k], bs[3][k]));
        float ig = fast_sigmoid(pi);
        float fg = fast_sigmoid(pf);
        float gg = fast_tanh(pg);
        float og = fast_sigmoid(po);
        cc[k] = fmaf(fg, cc[k], ig * gg);
        r += og * fast_tanh(cc[k]) * whr[k];
      }
      r = wave_sum(r);
      h = r;
      outv = (lane == s) ? r : outv;
    }

    if (l < 4) {
      if (lane < CH)
        __hip_atomic_store(out + c * CH + lane, outv, __ATOMIC_RELAXED,
                           __HIP_MEMORY_SCOPE_AGENT);
      if (lane == 0)
        __hip_atomic_store(my_flag, c + 1, __ATOMIC_RELEASE,
                           __HIP_MEMORY_SCOPE_AGENT);
    } else {
      // layer 4: consumed by the next kernel launch (stream-ordered) — plain store
      if (lane < CH) out[c * CH + lane] = outv;
    }
  }
}

__global__ __launch_bounds__(128) void mlp_head_kernel(
    const float* __restrict__ seq4,  // [B, T] layer-4 outputs
    const float* __restrict__ W1, const float* __restrict__ b1,
    const float* __restrict__ W2, const float* __restrict__ b2,
    const float* __restrict__ W3, const float* __restrict__ b3,
    const float* __restrict__ W4, const float* __restrict__ b4,
    float* __restrict__ out)         // [B]
{
  __shared__ float sx[TT];
  __shared__ float sh[100];
  __shared__ float sh2[100];
  __shared__ float red[2];

  const int b = blockIdx.x, tid = threadIdx.x;
  for (int i = tid; i < TT; i += 128) sx[i] = seq4[b * TT + i];
  __syncthreads();

  if (tid < 100) {
    const float* w = W1 + tid * TT;
    float a0 = 0.f, a1 = 0.f, a2 = 0.f, a3 = 0.f;  // 4 independent chains
    for (int t0 = 0; t0 < TT; t0 += 4) {
      float4 v = *(const float4*)(w + t0);
      a0 = fmaf(v.x, sx[t0 + 0], a0);
      a1 = fmaf(v.y, sx[t0 + 1], a1);
      a2 = fmaf(v.z, sx[t0 + 2], a2);
      a3 = fmaf(v.w, sx[t0 + 3], a3);
    }
    sh[tid] = fast_sigmoid((a0 + a1) + (a2 + a3) + b1[tid]);
  }
  __syncthreads();

  if (tid < 100) {
    float acc = b2[tid];
    const float* w = W2 + tid * 100;
    for (int k = 0; k < 100; ++k) acc += w[k] * sh[k];
    sh2[tid] = fast_sigmoid(acc);
  }
  __syncthreads();

  if (tid < 100) {
    float acc = b3[tid];
    const float* w = W3 + tid * 100;
    for (int k = 0; k < 100; ++k) acc += w[k] * sh2[k];
    sh[tid] = fmaxf(acc, 0.0f);
  }
  __syncthreads();

  float r = (tid < 100) ? sh[tid] * W4[tid] : 0.0f;
  {  // wave sum
    r = dpp_add<0x128>(r);
    r = dpp_add<0x124>(r);
    r = dpp_add<0x122>(r);
    r = dpp_add<0x121>(r);
    int sw = __builtin_amdgcn_ds_swizzle(__builtin_bit_cast(int, r), 0x401F);
    r = r + __builtin_bit_cast(float, sw);
    float lo = __builtin_bit_cast(float, __builtin_amdgcn_readlane(__builtin_bit_cast(int, r), 0));
    float hi = __builtin_bit_cast(float, __builtin_amdgcn_readlane(__builtin_bit_cast(int, r), 32));
    r = lo + hi;
  }
  if ((tid & 63) == 0) red[tid >> 6] = r;
  __syncthreads();
  if (tid == 0) out[b] = red[0] + red[1] + b4[0];
}

extern "C" void kernel_launch(void* const* d_in, const int* in_sizes, int n_in,
                              void* d_out, int out_size, void* d_ws, size_t ws_size,
                              hipStream_t stream) {
  const float* x   = (const float*)d_in[0];
  const float* Wih = (const float*)d_in[1];
  const float* Whh = (const float*)d_in[2];
  const float* bih = (const float*)d_in[3];
  const float* bhh = (const float*)d_in[4];
  const float* Whr = (const float*)d_in[5];
  const float* W1  = (const float*)d_in[6];
  const float* b1  = (const float*)d_in[7];
  const float* W2  = (const float*)d_in[8];
  const float* b2  = (const float*)d_in[9];
  const float* W3  = (const float*)d_in[10];
  const float* b3  = (const float*)d_in[11];
  const float* W4  = (const float*)d_in[12];
  const float* b4  = (const float*)d_in[13];

  float* seq   = (float*)d_ws;                       // [5][128][1000] f32 = 2.56 MB
  int*   flags = (int*)(seq + LAYERS * BATCH * TT);  // [5][128] int

  hipMemsetAsync(flags, 0, LAYERS * BATCH * sizeof(int), stream);
  lstm_wave_kernel<<<LAYERS * BATCH, 64, 0, stream>>>(x, Wih, Whh, bih, bhh, Whr,
                                                      seq, flags);
  mlp_head_kernel<<<BATCH, 128, 0, stream>>>(seq + 4 * BATCH * TT,
                                             W1, b1, W2, b2, W3, b3, W4, b4,
                                             (float*)d_out);
}

// Round 4
// 558.138 us; speedup vs baseline: 1.2369x; 1.1209x over previous
//
#include <hip/hip_runtime.h>

// voltageNN: 5-layer projected LSTM (H=256, P=1) over T=1000, B=128 + MLP head.
// R4: decoupled wave-per-(layer,batch) pipeline (proven R3) with the per-step
// dependency chain attacked:
//   - cell computation phase-structured (gx fmafs | h fmafs | exp2s | rcps)
//     so all 4 k-subcells stay in flight (R3's VGPR=40 showed the compiler
//     serialized them; per-step chain ~1140 cyc, issue only ~430).
//   - weights pre-scaled by -log2e (i,f,o) / -2log2e (g): exp2 arg is ONE
//     fmaf away from h.
//   - allreduce: 4x row_ror + row_bcast15 + row_bcast31 DPP adds + readlane63
//     (h lives in an SGPR) -- replaces ds_swizzle (~120 cyc DS latency).
// Communication protocol (agent-scope acquire/release flags) unchanged from R3.

#define LAYERS 5
#define TT 1000
#define BATCH 128
#define CH 40            // chunk length (divides TT)
#define NCH (TT / CH)    // 25 chunks

#define LOG2E 1.4426950408889634f

__device__ __forceinline__ float fast_exp2(float x) {
#if __has_builtin(__builtin_amdgcn_exp2f)
  return __builtin_amdgcn_exp2f(x);
#else
  return __exp2f(x);
#endif
}
__device__ __forceinline__ float fast_rcp(float x) {
#if __has_builtin(__builtin_amdgcn_rcpf)
  return __builtin_amdgcn_rcpf(x);
#else
  return 1.0f / x;
#endif
}
// sigmoid for the MLP head (unscaled weights there)
__device__ __forceinline__ float fast_sigmoid(float z) {
  float e = fast_exp2(-LOG2E * z);
  return fast_rcp(1.0f + e);
}

template <int CTRL>
__device__ __forceinline__ float dpp_add(float v) {
  int moved = __builtin_amdgcn_update_dpp(0, __builtin_bit_cast(int, v),
                                          CTRL, 0xF, 0xF, false);
  return v + __builtin_bit_cast(float, moved);
}

// Wave64 total, returned wave-uniform (SGPR via readlane 63).
// row_ror 8/4/2/1 -> every lane holds its row-of-16 sum; row_bcast15 adds R0
// into row1 (R2 into row3); row_bcast31 adds (R0+R1) into rows 2,3 -> lanes
// 48..63 hold the full sum.
__device__ __forceinline__ float wave_sum_uniform(float v) {
  v = dpp_add<0x128>(v);  // row_ror:8
  v = dpp_add<0x124>(v);  // row_ror:4
  v = dpp_add<0x122>(v);  // row_ror:2
  v = dpp_add<0x121>(v);  // row_ror:1
  v = dpp_add<0x142>(v);  // row_bcast:15
  v = dpp_add<0x143>(v);  // row_bcast:31
  return __builtin_bit_cast(float, __builtin_amdgcn_readlane(__builtin_bit_cast(int, v), 63));
}

__device__ __forceinline__ float lane_bcast(float v, int s) {
  return __builtin_bit_cast(float, __builtin_amdgcn_readlane(__builtin_bit_cast(int, v), s));
}

__global__ __launch_bounds__(64) void lstm_wave_kernel(
    const float* __restrict__ x,     // [B, T]
    const float* __restrict__ Wih,   // [L, 1024]
    const float* __restrict__ Whh,   // [L, 1024]
    const float* __restrict__ bih,   // [L, 1024]
    const float* __restrict__ bhh,   // [L, 1024]
    const float* __restrict__ Whr,   // [L, 256]
    float* __restrict__ seq,         // [L, B, T] layer outputs (workspace)
    int* __restrict__ flags)         // [L, B] chunk progress counters
{
  const int bid  = blockIdx.x;
  const int l    = bid >> 7;   // bid / 128
  const int b    = bid & 127;  // bid % 128
  const int lane = threadIdx.x;

  // per-lane weights, pre-scaled into the exp2 domain.
  // gate order: 0=i, 1=f, 2=g(tanh), 3=o.  E[g] = exp2(sc*(pre-activation))
  // with sc = -log2e for sigmoid gates, -2log2e for the tanh gate.
  float wix[4][4], whx[4][4], gb[4][4], whr[4], cc[4];
  const int base = l * 1024;
#pragma unroll
  for (int g = 0; g < 4; ++g) {
    const float sc = (g == 2) ? (-2.0f * LOG2E) : (-LOG2E);
#pragma unroll
    for (int k = 0; k < 4; ++k) {
      int j = base + g * 256 + k * 64 + lane;
      wix[g][k] = Wih[j] * sc;
      whx[g][k] = Whh[j] * sc;
      gb[g][k]  = (bih[j] + bhh[j]) * sc;
    }
  }
#pragma unroll
  for (int k = 0; k < 4; ++k) {
    whr[k] = Whr[l * 256 + k * 64 + lane];
    cc[k] = 0.0f;
  }

  const float* in  = (l == 0) ? (x + b * TT) : (seq + ((l - 1) * BATCH + b) * TT);
  float*       out = seq + (l * BATCH + b) * TT;
  int*       my_flag = flags + l * BATCH + b;
  const int* in_flag = (l > 0) ? (flags + (l - 1) * BATCH + b) : (const int*)flags;

  float h = 0.0f;
  for (int c = 0; c < NCH; ++c) {
    if (l > 0) {
      while (__hip_atomic_load(in_flag, __ATOMIC_ACQUIRE,
                               __HIP_MEMORY_SCOPE_AGENT) <= c)
        __builtin_amdgcn_s_sleep(2);
    }
    float xv = 0.0f;
    if (lane < CH) {
      if (l == 0)
        xv = in[c * CH + lane];
      else
        xv = __hip_atomic_load(in + c * CH + lane, __ATOMIC_RELAXED,
                               __HIP_MEMORY_SCOPE_AGENT);
    }

    float outv = 0.0f;
#pragma unroll 2
    for (int s = 0; s < CH; ++s) {
      const float xs = lane_bcast(xv, s);

      // phase A: h-independent part of all 16 pre-activations
      float gx[4][4];
#pragma unroll
      for (int g = 0; g < 4; ++g)
#pragma unroll
        for (int k = 0; k < 4; ++k)
          gx[g][k] = fmaf(xs, wix[g][k], gb[g][k]);

      // phase B+C: one fmaf from h, then exp2 (all 16 independent)
      float E[4][4];
#pragma unroll
      for (int g = 0; g < 4; ++g)
#pragma unroll
        for (int k = 0; k < 4; ++k)
          E[g][k] = fast_exp2(fmaf(h, whx[g][k], gx[g][k]));

      // phase D: gate combines, cell update, projection partial (k's independent)
      float r0, r1, r2, r3;
      {
        float rr[4];
#pragma unroll
        for (int k = 0; k < 4; ++k) {
          float ig = fast_rcp(1.0f + E[0][k]);
          float fg = fast_rcp(1.0f + E[1][k]);
          float gg = fmaf(2.0f, fast_rcp(1.0f + E[2][k]), -1.0f);
          float og = fast_rcp(1.0f + E[3][k]);
          cc[k] = fmaf(fg, cc[k], ig * gg);
          float tE = fast_exp2(cc[k] * (-2.0f * LOG2E));
          float tc = fmaf(2.0f, fast_rcp(1.0f + tE), -1.0f);
          rr[k] = og * tc * whr[k];
        }
        r0 = rr[0]; r1 = rr[1]; r2 = rr[2]; r3 = rr[3];
      }
      float r = (r0 + r1) + (r2 + r3);

      h = wave_sum_uniform(r);     // SGPR-uniform h(t)
      if (lane == s) outv = h;
    }

    if (l < 4) {
      if (lane < CH)
        __hip_atomic_store(out + c * CH + lane, outv, __ATOMIC_RELAXED,
                           __HIP_MEMORY_SCOPE_AGENT);
      if (lane == 0)
        __hip_atomic_store(my_flag, c + 1, __ATOMIC_RELEASE,
                           __HIP_MEMORY_SCOPE_AGENT);
    } else {
      if (lane < CH) out[c * CH + lane] = outv;  // consumed by next launch
    }
  }
}

__global__ __launch_bounds__(256) void mlp_head_kernel(
    const float* __restrict__ seq4,  // [B, T] layer-4 outputs
    const float* __restrict__ W1, const float* __restrict__ b1,
    const float* __restrict__ W2, const float* __restrict__ b2,
    const float* __restrict__ W3, const float* __restrict__ b3,
    const float* __restrict__ W4, const float* __restrict__ b4,
    float* __restrict__ out)         // [B]
{
  __shared__ float sx[TT];
  __shared__ float sh[100];
  __shared__ float sh2[100];
  __shared__ float part[100];
  __shared__ float red[4];

  const int b = blockIdx.x, tid = threadIdx.x;
  for (int i = tid; i < TT; i += 256) sx[i] = seq4[b * TT + i];
  __syncthreads();

  // phase 1: 2 threads per output (tid<100: t in [0,500); tid in [128,228): [500,1000))
  const int half = (tid >= 128) ? 1 : 0;
  const int oid  = half ? (tid - 128) : tid;
  float myacc = 0.0f;
  if (oid < 100) {
    const float* w  = W1 + oid * TT + half * 500;
    const float* xx = sx + half * 500;
    float a0 = 0.f, a1 = 0.f, a2 = 0.f, a3 = 0.f;
    for (int t0 = 0; t0 < 500; t0 += 4) {
      float4 v = *(const float4*)(w + t0);
      a0 = fmaf(v.x, xx[t0 + 0], a0);
      a1 = fmaf(v.y, xx[t0 + 1], a1);
      a2 = fmaf(v.z, xx[t0 + 2], a2);
      a3 = fmaf(v.w, xx[t0 + 3], a3);
    }
    myacc = (a0 + a1) + (a2 + a3);
    if (half) part[oid] = myacc;
  }
  __syncthreads();
  if (tid < 100) sh[tid] = fast_sigmoid(myacc + part[tid] + b1[tid]);
  __syncthreads();

  if (tid < 100) {
    float acc = b2[tid];
    const float* w = W2 + tid * 100;
    for (int k = 0; k < 100; ++k) acc += w[k] * sh[k];
    sh2[tid] = fast_sigmoid(acc);
  }
  __syncthreads();

  if (tid < 100) {
    float acc = b3[tid];
    const float* w = W3 + tid * 100;
    for (int k = 0; k < 100; ++k) acc += w[k] * sh2[k];
    sh[tid] = fmaxf(acc, 0.0f);
  }
  __syncthreads();

  float r = (tid < 100) ? sh[tid] * W4[tid] : 0.0f;
  {  // wave sum (any-lane result on lane floor; use bcast path)
    r = dpp_add<0x128>(r);
    r = dpp_add<0x124>(r);
    r = dpp_add<0x122>(r);
    r = dpp_add<0x121>(r);
    r = dpp_add<0x142>(r);
    r = dpp_add<0x143>(r);
    r = __builtin_bit_cast(float, __builtin_amdgcn_readlane(__builtin_bit_cast(int, r), 63));
  }
  if ((tid & 63) == 0) red[tid >> 6] = r;
  __syncthreads();
  if (tid == 0) out[b] = (red[0] + red[1]) + (red[2] + red[3]) + b4[0];
}

extern "C" void kernel_launch(void* const* d_in, const int* in_sizes, int n_in,
                              void* d_out, int out_size, void* d_ws, size_t ws_size,
                              hipStream_t stream) {
  const float* x   = (const float*)d_in[0];
  const float* Wih = (const float*)d_in[1];
  const float* Whh = (const float*)d_in[2];
  const float* bih = (const float*)d_in[3];
  const float* bhh = (const float*)d_in[4];
  const float* Whr = (const float*)d_in[5];
  const float* W1  = (const float*)d_in[6];
  const float* b1  = (const float*)d_in[7];
  const float* W2  = (const float*)d_in[8];
  const float* b2  = (const float*)d_in[9];
  const float* W3  = (const float*)d_in[10];
  const float* b3  = (const float*)d_in[11];
  const float* W4  = (const float*)d_in[12];
  const float* b4  = (const float*)d_in[13];

  float* seq   = (float*)d_ws;                       // [5][128][1000] f32 = 2.56 MB
  int*   flags = (int*)(seq + LAYERS * BATCH * TT);  // [5][128] int

  hipMemsetAsync(flags, 0, LAYERS * BATCH * sizeof(int), stream);
  lstm_wave_kernel<<<LAYERS * BATCH, 64, 0, stream>>>(x, Wih, Whh, bih, bhh, Whr,
                                                      seq, flags);
  mlp_head_kernel<<<BATCH, 256, 0, stream>>>(seq + 4 * BATCH * TT,
                                             W1, b1, W2, b2, W3, b3, W4, b4,
                                             (float*)d_out);
}